// Round 3
// baseline (1431.884 us; speedup 1.0000x reference)
//
#include <hip/hip_runtime.h>

#define D 128
#define NHB 256            // blocks for hist/scatter passes
#define MAXBUC 2048        // LDS capacity for bucket counters (N <= 131072)

// ---------------- prep ----------------

__global__ __launch_bounds__(256) void k_transpose_w(const float* __restrict__ W,
                                                     float* __restrict__ Wt) {
  int t = blockIdx.x * 256 + threadIdx.x;
  int o = t >> 7;
  int k = t & 127;
  Wt[k * D + o] = W[o * D + k];
}

// ---------------- bucketed CSR-free build (no global atomics) ----------------
// bucket(node) = node >> 6  (64 nodes per bucket)

// P1: per-block bucket histogram over this block's edge range
__global__ __launch_bounds__(256) void k_hist(const int* __restrict__ ei,
                                              int* __restrict__ hist, int E, int nbuc) {
  __shared__ int h[MAXBUC];
  for (int i = threadIdx.x; i < nbuc; i += 256) h[i] = 0;
  __syncthreads();
  int per = (E + NHB - 1) / NHB;
  int e0 = blockIdx.x * per, e1 = min(E, e0 + per);
  for (int e = e0 + threadIdx.x; e < e1; e += 256) {
    int r = ei[e], c = ei[E + e];
    atomicAdd(&h[c >> 6], 1);   // entry with dest c (src r)
    atomicAdd(&h[r >> 6], 1);   // entry with dest r (src c)
  }
  __syncthreads();
  for (int i = threadIdx.x; i < nbuc; i += 256)
    hist[blockIdx.x * nbuc + i] = h[i];
}

// P2a: column totals: tot[b] = sum_j hist[j][b]
__global__ __launch_bounds__(256) void k_coltotal(const int* __restrict__ hist,
                                                  int* __restrict__ tot, int nbuc) {
  int b = blockIdx.x * 256 + threadIdx.x;
  if (b < nbuc) {
    int s = 0;
    for (int j = 0; j < NHB; ++j) s += hist[j * nbuc + b];
    tot[b] = s;
  }
}

__global__ __launch_bounds__(256) void k_blocksum(const int* __restrict__ v,
                                                  int* __restrict__ bsum, int n) {
  __shared__ int s[256];
  int i = blockIdx.x * 256 + threadIdx.x;
  s[threadIdx.x] = (i < n) ? v[i] : 0;
  __syncthreads();
  for (int o = 128; o > 0; o >>= 1) {
    if (threadIdx.x < o) s[threadIdx.x] += s[threadIdx.x + o];
    __syncthreads();
  }
  if (threadIdx.x == 0) bsum[blockIdx.x] = s[0];
}

__global__ __launch_bounds__(512) void k_scanbsum(int* __restrict__ bsum, int nb) {
  __shared__ int s[512];
  int v = (threadIdx.x < nb) ? bsum[threadIdx.x] : 0;
  s[threadIdx.x] = v;
  __syncthreads();
  for (int o = 1; o < 512; o <<= 1) {
    int t = (threadIdx.x >= (unsigned)o) ? s[threadIdx.x - o] : 0;
    __syncthreads();
    s[threadIdx.x] += t;
    __syncthreads();
  }
  if (threadIdx.x < nb) bsum[threadIdx.x] = s[threadIdx.x] - v;  // exclusive
}

// P2b: bucketOff[b] = exclusive scan of tot; bucketOff[nbuc] = total
__global__ __launch_bounds__(256) void k_bucketoff(const int* __restrict__ tot,
                                                   const int* __restrict__ bofs,
                                                   int* __restrict__ boff, int n) {
  __shared__ int s[256];
  int i = blockIdx.x * 256 + threadIdx.x;
  int v = (i < n) ? tot[i] : 0;
  s[threadIdx.x] = v;
  __syncthreads();
  for (int o = 1; o < 256; o <<= 1) {
    int t = (threadIdx.x >= (unsigned)o) ? s[threadIdx.x - o] : 0;
    __syncthreads();
    s[threadIdx.x] += t;
    __syncthreads();
  }
  if (i < n) {
    int incl = s[threadIdx.x] + bofs[blockIdx.x];
    boff[i] = incl - v;
    if (i == n - 1) boff[n] = incl;
  }
}

// P2c: blockStart[j][b] = boff[b] + sum_{j'<j} hist[j'][b]
__global__ __launch_bounds__(256) void k_blockstart(const int* __restrict__ hist,
                                                    const int* __restrict__ boff,
                                                    int* __restrict__ bstart, int nbuc) {
  __shared__ int s[256];
  int b = blockIdx.x;
  int j = threadIdx.x;
  int v = hist[j * nbuc + b];
  s[j] = v;
  __syncthreads();
  for (int o = 1; o < 256; o <<= 1) {
    int t = (j >= (unsigned)o) ? s[j - o] : 0;
    __syncthreads();
    s[j] += t;
    __syncthreads();
  }
  bstart[j * nbuc + b] = boff[b] + s[j] - v;
}

// P3: scatter packed entries (src<<6 | dest&63) using LDS cursors (no global atomics)
__global__ __launch_bounds__(256) void k_scatter2(const int* __restrict__ ei,
                                                  const int* __restrict__ bstart,
                                                  int* __restrict__ entries,
                                                  int E, int nbuc) {
  __shared__ int cur[MAXBUC];
  for (int i = threadIdx.x; i < nbuc; i += 256)
    cur[i] = bstart[blockIdx.x * nbuc + i];
  __syncthreads();
  int per = (E + NHB - 1) / NHB;
  int e0 = blockIdx.x * per, e1 = min(E, e0 + per);
  for (int e = e0 + threadIdx.x; e < e1; e += 256) {
    int r = ei[e], c = ei[E + e];
    int p1 = atomicAdd(&cur[c >> 6], 1);
    entries[p1] = (r << 6) | (c & 63);
    int p2 = atomicAdd(&cur[r >> 6], 1);
    entries[p2] = (c << 6) | (r & 63);
  }
}

// P4: dis[node] = rsqrt(sym_degree + 1) from per-bucket LDS counts
__global__ __launch_bounds__(256) void k_dis2(const int* __restrict__ entries,
                                              const int* __restrict__ boff,
                                              float* __restrict__ dis, int N) {
  __shared__ int cnt[64];
  if (threadIdx.x < 64) cnt[threadIdx.x] = 0;
  __syncthreads();
  int s = boff[blockIdx.x], e = boff[blockIdx.x + 1];
  for (int i = s + threadIdx.x; i < e; i += 256) atomicAdd(&cnt[entries[i] & 63], 1);
  __syncthreads();
  if (threadIdx.x < 64) {
    int gn = blockIdx.x * 64 + threadIdx.x;
    if (gn < N) dis[gn] = rsqrtf((float)(cnt[threadIdx.x] + 1));
  }
}

// ---------------- fused GEMM: g = dis * (x @ W^T + b) ----------------
__global__ __launch_bounds__(256) void k_gemm(
    const float* __restrict__ x, const float* __restrict__ Wt,
    const float* __restrict__ bias, const float* __restrict__ dis,
    float* __restrict__ g, int n) {
  __shared__ float swt[D * D];
  __shared__ float sxt[D][32];

  for (int i = threadIdx.x; i < D * D; i += 256) swt[i] = Wt[i];

  const int co = threadIdx.x & 31;
  const int rq = threadIdx.x >> 5;
  const float4 b4 = ((const float4*)bias)[co];
  const int row0 = blockIdx.x * 128;

  for (int batch = 0; batch < 4; ++batch) {
    const int base = row0 + batch * 32;
    __syncthreads();
    for (int j = 0; j < 4; ++j) {
      int idx = threadIdx.x + j * 256;
      int r = idx >> 5;
      int kg = idx & 31;
      int grow = base + r;
      float4 v = make_float4(0.f, 0.f, 0.f, 0.f);
      if (grow < n) v = ((const float4*)x)[(size_t)grow * 32 + kg];
      sxt[4 * kg + 0][r] = v.x;
      sxt[4 * kg + 1][r] = v.y;
      sxt[4 * kg + 2][r] = v.z;
      sxt[4 * kg + 3][r] = v.w;
    }
    __syncthreads();

    float4 a0 = b4, a1 = b4, a2 = b4, a3 = b4;
#pragma unroll 8
    for (int k = 0; k < D; ++k) {
      const float4 w4 = *(const float4*)(swt + k * D + 4 * co);
      const float4 x4 = *(const float4*)(&sxt[k][4 * rq]);
      a0.x = fmaf(x4.x, w4.x, a0.x); a0.y = fmaf(x4.x, w4.y, a0.y);
      a0.z = fmaf(x4.x, w4.z, a0.z); a0.w = fmaf(x4.x, w4.w, a0.w);
      a1.x = fmaf(x4.y, w4.x, a1.x); a1.y = fmaf(x4.y, w4.y, a1.y);
      a1.z = fmaf(x4.y, w4.z, a1.z); a1.w = fmaf(x4.y, w4.w, a1.w);
      a2.x = fmaf(x4.z, w4.x, a2.x); a2.y = fmaf(x4.z, w4.y, a2.y);
      a2.z = fmaf(x4.z, w4.z, a2.z); a2.w = fmaf(x4.z, w4.w, a2.w);
      a3.x = fmaf(x4.w, w4.x, a3.x); a3.y = fmaf(x4.w, w4.y, a3.y);
      a3.z = fmaf(x4.w, w4.z, a3.z); a3.w = fmaf(x4.w, w4.w, a3.w);
    }

    const int r = base + rq * 4;
    float4 accs[4] = {a0, a1, a2, a3};
#pragma unroll
    for (int j = 0; j < 4; ++j) {
      int rr = r + j;
      if (rr < n) {
        float s = dis[rr];
        float4 a = accs[j];
        a.x *= s; a.y *= s; a.z *= s; a.w *= s;
        ((float4*)g)[(size_t)rr * 32 + co] = a;
      }
    }
  }
}

// ---------------- P5: per-bucket aggregation with LDS f32 accumulator tile ----------------
// out[v] = relu(dis[v] * (g[v] + sum_{entries dest=v} g[src]))
__global__ __launch_bounds__(256) void k_agg2(const int* __restrict__ entries,
                                              const int* __restrict__ boff,
                                              const float* __restrict__ g,
                                              const float* __restrict__ dis,
                                              float* __restrict__ out, int N) {
  __shared__ float acc[64 * D];   // 32 KB
  const int b = blockIdx.x;
  const int base_node = b * 64;

  // init with self term (g already dis-scaled, bias included)
  for (int idx = threadIdx.x; idx < 64 * 32; idx += 256) {
    int n0 = idx >> 5, j = idx & 31;
    int gn = base_node + n0;
    float4 v = make_float4(0.f, 0.f, 0.f, 0.f);
    if (gn < N) v = ((const float4*)g)[(size_t)gn * 32 + j];
    ((float4*)acc)[idx] = v;
  }
  __syncthreads();

  const int s = boff[b], e = boff[b + 1];
  const int wid = threadIdx.x >> 6, lane = threadIdx.x & 63;
  const float2* g2 = (const float2*)g;

  for (int base = s + wid * 64; base < e; base += 256) {
    int cnt = e - base; if (cnt > 64) cnt = 64;
    int my = (base + lane < e) ? entries[base + lane] : 0;
    for (int k = 0; k < cnt; ++k) {
      int en = __shfl(my, k);
      int src = en >> 6;
      int ld = en & 63;
      float2 v = g2[(size_t)src * 64 + lane];
      atomicAdd(&acc[ld * D + 2 * lane], v.x);
      atomicAdd(&acc[ld * D + 2 * lane + 1], v.y);
    }
  }
  __syncthreads();

  for (int idx = threadIdx.x; idx < 64 * 32; idx += 256) {
    int n0 = idx >> 5, j = idx & 31;
    int gn = base_node + n0;
    if (gn < N) {
      float sc = dis[gn];
      float4 v = ((float4*)acc)[idx];
      v.x = fmaxf(v.x * sc, 0.f);
      v.y = fmaxf(v.y * sc, 0.f);
      v.z = fmaxf(v.z * sc, 0.f);
      v.w = fmaxf(v.w * sc, 0.f);
      ((float4*)out)[(size_t)gn * 32 + j] = v;
    }
  }
}

extern "C" void kernel_launch(void* const* d_in, const int* in_sizes, int n_in,
                              void* d_out, int out_size, void* d_ws, size_t ws_size,
                              hipStream_t stream) {
  const float* x  = (const float*)d_in[0];
  const int*   ei = (const int*)d_in[1];
  const float* W  = (const float*)d_in[2];
  const float* b  = (const float*)d_in[3];
  float* out = (float*)d_out;

  const int N = in_sizes[0] / D;
  const int E = in_sizes[1] / 2;
  const int NBUC = (N + 63) / 64;            // 1563 for N=100k (<= MAXBUC)
  const int nb2 = (NBUC + 255) / 256;        // 7

  char* ws = (char*)d_ws;
  size_t off = 0;
  float* Wt   = (float*)(ws + off); off += (size_t)D * D * 4;        // 64 KB
  float* dis  = (float*)(ws + off); off += (size_t)N * 4;
  off = (off + 255) & ~(size_t)255;
  int* tot    = (int*)(ws + off);   off += (size_t)NBUC * 4;
  int* bsum   = (int*)(ws + off);   off += (size_t)512 * 4;
  int* boff   = (int*)(ws + off);   off += (size_t)(NBUC + 1) * 4;
  off = (off + 255) & ~(size_t)255;
  int* entries = (int*)(ws + off);  off += (size_t)2 * E * 4;        // 6.4 MB
  off = (off + 255) & ~(size_t)255;
  // union region: hist+bstart (3.2 MB, dead after k_scatter2) overlaps g (51.2 MB)
  int* hist    = (int*)(ws + off);
  int* bstart  = hist + (size_t)NHB * NBUC;
  float* g     = (float*)(ws + off);

  k_transpose_w<<<(D * D + 255) / 256, 256, 0, stream>>>(W, Wt);
  k_hist<<<NHB, 256, 0, stream>>>(ei, hist, E, NBUC);
  k_coltotal<<<nb2, 256, 0, stream>>>(hist, tot, NBUC);
  k_blocksum<<<nb2, 256, 0, stream>>>(tot, bsum, NBUC);
  k_scanbsum<<<1, 512, 0, stream>>>(bsum, nb2);
  k_bucketoff<<<nb2, 256, 0, stream>>>(tot, bsum, boff, NBUC);
  k_blockstart<<<NBUC, 256, 0, stream>>>(hist, boff, bstart, NBUC);
  k_scatter2<<<NHB, 256, 0, stream>>>(ei, bstart, entries, E, NBUC);
  k_dis2<<<NBUC, 256, 0, stream>>>(entries, boff, dis, N);
  k_gemm<<<(N + 127) / 128, 256, 0, stream>>>(x, Wt, b, dis, g, N);   // overwrites hist/bstart
  k_agg2<<<NBUC, 256, 0, stream>>>(entries, boff, g, dis, out, N);
}

// Round 4
// 350.154 us; speedup vs baseline: 4.0893x; 4.0893x over previous
//
#include <hip/hip_runtime.h>

#define D 128
#define NHB 256            // blocks for hist/scatter passes
#define MAXBUC 2048        // LDS capacity for bucket counters (N <= 131072)

// ---------------- prep ----------------

__global__ __launch_bounds__(256) void k_transpose_w(const float* __restrict__ W,
                                                     float* __restrict__ Wt) {
  int t = blockIdx.x * 256 + threadIdx.x;
  int o = t >> 7;
  int k = t & 127;
  Wt[k * D + o] = W[o * D + k];
}

// ---------------- bucketed CSR-free build (no global atomics) ----------------
// bucket(node) = node >> 6  (64 nodes per bucket)

// P1: per-block bucket histogram over this block's edge range
__global__ __launch_bounds__(256) void k_hist(const int* __restrict__ ei,
                                              int* __restrict__ hist, int E, int nbuc) {
  __shared__ int h[MAXBUC];
  for (int i = threadIdx.x; i < nbuc; i += 256) h[i] = 0;
  __syncthreads();
  int per = (E + NHB - 1) / NHB;
  int e0 = blockIdx.x * per, e1 = min(E, e0 + per);
  for (int e = e0 + threadIdx.x; e < e1; e += 256) {
    int r = ei[e], c = ei[E + e];
    atomicAdd(&h[c >> 6], 1);   // entry with dest c (src r)
    atomicAdd(&h[r >> 6], 1);   // entry with dest r (src c)
  }
  __syncthreads();
  for (int i = threadIdx.x; i < nbuc; i += 256)
    hist[blockIdx.x * nbuc + i] = h[i];
}

// P2a: column totals: tot[b] = sum_j hist[j][b]
__global__ __launch_bounds__(256) void k_coltotal(const int* __restrict__ hist,
                                                  int* __restrict__ tot, int nbuc) {
  int b = blockIdx.x * 256 + threadIdx.x;
  if (b < nbuc) {
    int s = 0;
    for (int j = 0; j < NHB; ++j) s += hist[j * nbuc + b];
    tot[b] = s;
  }
}

__global__ __launch_bounds__(256) void k_blocksum(const int* __restrict__ v,
                                                  int* __restrict__ bsum, int n) {
  __shared__ int s[256];
  int i = blockIdx.x * 256 + threadIdx.x;
  s[threadIdx.x] = (i < n) ? v[i] : 0;
  __syncthreads();
  for (int o = 128; o > 0; o >>= 1) {
    if (threadIdx.x < o) s[threadIdx.x] += s[threadIdx.x + o];
    __syncthreads();
  }
  if (threadIdx.x == 0) bsum[blockIdx.x] = s[0];
}

__global__ __launch_bounds__(512) void k_scanbsum(int* __restrict__ bsum, int nb) {
  __shared__ int s[512];
  int v = (threadIdx.x < nb) ? bsum[threadIdx.x] : 0;
  s[threadIdx.x] = v;
  __syncthreads();
  for (int o = 1; o < 512; o <<= 1) {
    int t = (threadIdx.x >= (unsigned)o) ? s[threadIdx.x - o] : 0;
    __syncthreads();
    s[threadIdx.x] += t;
    __syncthreads();
  }
  if (threadIdx.x < nb) bsum[threadIdx.x] = s[threadIdx.x] - v;  // exclusive
}

// P2b: bucketOff[b] = exclusive scan of tot; bucketOff[nbuc] = total
__global__ __launch_bounds__(256) void k_bucketoff(const int* __restrict__ tot,
                                                   const int* __restrict__ bofs,
                                                   int* __restrict__ boff, int n) {
  __shared__ int s[256];
  int i = blockIdx.x * 256 + threadIdx.x;
  int v = (i < n) ? tot[i] : 0;
  s[threadIdx.x] = v;
  __syncthreads();
  for (int o = 1; o < 256; o <<= 1) {
    int t = (threadIdx.x >= (unsigned)o) ? s[threadIdx.x - o] : 0;
    __syncthreads();
    s[threadIdx.x] += t;
    __syncthreads();
  }
  if (i < n) {
    int incl = s[threadIdx.x] + bofs[blockIdx.x];
    boff[i] = incl - v;
    if (i == n - 1) boff[n] = incl;
  }
}

// P2c: blockStart[j][b] = boff[b] + sum_{j'<j} hist[j'][b]
__global__ __launch_bounds__(256) void k_blockstart(const int* __restrict__ hist,
                                                    const int* __restrict__ boff,
                                                    int* __restrict__ bstart, int nbuc) {
  __shared__ int s[256];
  int b = blockIdx.x;
  int j = threadIdx.x;
  int v = hist[j * nbuc + b];
  s[j] = v;
  __syncthreads();
  for (int o = 1; o < 256; o <<= 1) {
    int t = (j >= (unsigned)o) ? s[j - o] : 0;
    __syncthreads();
    s[j] += t;
    __syncthreads();
  }
  bstart[j * nbuc + b] = boff[b] + s[j] - v;
}

// P3: scatter packed entries (src<<6 | dest&63) using LDS int cursors (native)
__global__ __launch_bounds__(256) void k_scatter2(const int* __restrict__ ei,
                                                  const int* __restrict__ bstart,
                                                  int* __restrict__ entries,
                                                  int E, int nbuc) {
  __shared__ int cur[MAXBUC];
  for (int i = threadIdx.x; i < nbuc; i += 256)
    cur[i] = bstart[blockIdx.x * nbuc + i];
  __syncthreads();
  int per = (E + NHB - 1) / NHB;
  int e0 = blockIdx.x * per, e1 = min(E, e0 + per);
  for (int e = e0 + threadIdx.x; e < e1; e += 256) {
    int r = ei[e], c = ei[E + e];
    int p1 = atomicAdd(&cur[c >> 6], 1);
    entries[p1] = (r << 6) | (c & 63);
    int p2 = atomicAdd(&cur[r >> 6], 1);
    entries[p2] = (c << 6) | (r & 63);
  }
}

// P4: per-bucket counting sort by dest node -> srcs[] contiguous per node,
// nodeoff[N+1], dis[N]. Int LDS atomics only (native ds ops).
__global__ __launch_bounds__(256) void k_sortbuc(const int* __restrict__ entries,
                                                 const int* __restrict__ boff,
                                                 int* __restrict__ srcs,
                                                 int* __restrict__ nodeoff,
                                                 float* __restrict__ dis, int N) {
  __shared__ int bin[64];
  __shared__ int sc[64];
  const int b = blockIdx.x;
  const int s = boff[b], e = boff[b + 1];

  if (threadIdx.x < 64) bin[threadIdx.x] = 0;
  __syncthreads();
  for (int i = s + threadIdx.x; i < e; i += 256)
    atomicAdd(&bin[entries[i] & 63], 1);
  __syncthreads();

  int v = (threadIdx.x < 64) ? bin[threadIdx.x] : 0;
  if (threadIdx.x < 64) sc[threadIdx.x] = v;
  __syncthreads();
  for (int o = 1; o < 64; o <<= 1) {
    int t = (threadIdx.x < 64 && threadIdx.x >= (unsigned)o) ? sc[threadIdx.x - o] : 0;
    __syncthreads();
    if (threadIdx.x < 64) sc[threadIdx.x] += t;
    __syncthreads();
  }
  if (threadIdx.x < 64) {
    int start = s + sc[threadIdx.x] - v;   // exclusive prefix + bucket base
    bin[threadIdx.x] = start;              // becomes cursor
    int gn = b * 64 + threadIdx.x;
    if (gn < N) {
      nodeoff[gn] = start;
      dis[gn] = rsqrtf((float)(v + 1));    // +1 self loop
      if (gn == N - 1) nodeoff[N] = e;
    }
  }
  __syncthreads();

  for (int i = s + threadIdx.x; i < e; i += 256) {
    int en = entries[i];
    int p = atomicAdd(&bin[en & 63], 1);
    srcs[p] = en >> 6;
  }
}

// ---------------- fused GEMM: g = dis * (x @ W^T + b) ----------------
__global__ __launch_bounds__(256) void k_gemm(
    const float* __restrict__ x, const float* __restrict__ Wt,
    const float* __restrict__ bias, const float* __restrict__ dis,
    float* __restrict__ g, int n) {
  __shared__ float swt[D * D];
  __shared__ float sxt[D][32];

  for (int i = threadIdx.x; i < D * D; i += 256) swt[i] = Wt[i];

  const int co = threadIdx.x & 31;
  const int rq = threadIdx.x >> 5;
  const float4 b4 = ((const float4*)bias)[co];
  const int row0 = blockIdx.x * 128;

  for (int batch = 0; batch < 4; ++batch) {
    const int base = row0 + batch * 32;
    __syncthreads();
    for (int j = 0; j < 4; ++j) {
      int idx = threadIdx.x + j * 256;
      int r = idx >> 5;
      int kg = idx & 31;
      int grow = base + r;
      float4 v = make_float4(0.f, 0.f, 0.f, 0.f);
      if (grow < n) v = ((const float4*)x)[(size_t)grow * 32 + kg];
      sxt[4 * kg + 0][r] = v.x;
      sxt[4 * kg + 1][r] = v.y;
      sxt[4 * kg + 2][r] = v.z;
      sxt[4 * kg + 3][r] = v.w;
    }
    __syncthreads();

    float4 a0 = b4, a1 = b4, a2 = b4, a3 = b4;
#pragma unroll 8
    for (int k = 0; k < D; ++k) {
      const float4 w4 = *(const float4*)(swt + k * D + 4 * co);
      const float4 x4 = *(const float4*)(&sxt[k][4 * rq]);
      a0.x = fmaf(x4.x, w4.x, a0.x); a0.y = fmaf(x4.x, w4.y, a0.y);
      a0.z = fmaf(x4.x, w4.z, a0.z); a0.w = fmaf(x4.x, w4.w, a0.w);
      a1.x = fmaf(x4.y, w4.x, a1.x); a1.y = fmaf(x4.y, w4.y, a1.y);
      a1.z = fmaf(x4.y, w4.z, a1.z); a1.w = fmaf(x4.y, w4.w, a1.w);
      a2.x = fmaf(x4.z, w4.x, a2.x); a2.y = fmaf(x4.z, w4.y, a2.y);
      a2.z = fmaf(x4.z, w4.z, a2.z); a2.w = fmaf(x4.z, w4.w, a2.w);
      a3.x = fmaf(x4.w, w4.x, a3.x); a3.y = fmaf(x4.w, w4.y, a3.y);
      a3.z = fmaf(x4.w, w4.z, a3.z); a3.w = fmaf(x4.w, w4.w, a3.w);
    }

    const int r = base + rq * 4;
    float4 accs[4] = {a0, a1, a2, a3};
#pragma unroll
    for (int j = 0; j < 4; ++j) {
      int rr = r + j;
      if (rr < n) {
        float s = dis[rr];
        float4 a = accs[j];
        a.x *= s; a.y *= s; a.z *= s; a.w *= s;
        ((float4*)g)[(size_t)rr * 32 + co] = a;
      }
    }
  }
}

// ---------------- P5: pull aggregation, one wave per node, register acc ----------------
// out[v] = relu(dis[v] * (g[v] + sum_{u in srcs[nodeoff[v]..nodeoff[v+1])} g[u]))
__global__ __launch_bounds__(256) void k_agg3(const int* __restrict__ nodeoff,
                                              const int* __restrict__ srcs,
                                              const float* __restrict__ g,
                                              const float* __restrict__ dis,
                                              float* __restrict__ out, int N) {
  int w = blockIdx.x * 4 + (threadIdx.x >> 6);
  if (w >= N) return;
  int lane = threadIdx.x & 63;
  const float2* g2 = (const float2*)g;

  float2 acc = g2[(size_t)w * 64 + lane];   // self-loop term
  int s = nodeoff[w];
  int e = nodeoff[w + 1];
  for (int base = s; base < e; base += 64) {
    int cnt = e - base; if (cnt > 64) cnt = 64;
    int my = (base + lane < e) ? srcs[base + lane] : 0;
    int k = 0;
    for (; k + 3 < cnt; k += 4) {           // 4 gathers in flight
      int u0 = __shfl(my, k);
      int u1 = __shfl(my, k + 1);
      int u2 = __shfl(my, k + 2);
      int u3 = __shfl(my, k + 3);
      float2 v0 = g2[(size_t)u0 * 64 + lane];
      float2 v1 = g2[(size_t)u1 * 64 + lane];
      float2 v2 = g2[(size_t)u2 * 64 + lane];
      float2 v3 = g2[(size_t)u3 * 64 + lane];
      acc.x += v0.x + v1.x + v2.x + v3.x;
      acc.y += v0.y + v1.y + v2.y + v3.y;
    }
    for (; k < cnt; ++k) {
      int u = __shfl(my, k);
      float2 v = g2[(size_t)u * 64 + lane];
      acc.x += v.x;
      acc.y += v.y;
    }
  }
  float sc = dis[w];
  float2 o;
  o.x = fmaxf(acc.x * sc, 0.f);
  o.y = fmaxf(acc.y * sc, 0.f);
  ((float2*)out)[(size_t)w * 64 + lane] = o;
}

extern "C" void kernel_launch(void* const* d_in, const int* in_sizes, int n_in,
                              void* d_out, int out_size, void* d_ws, size_t ws_size,
                              hipStream_t stream) {
  const float* x  = (const float*)d_in[0];
  const int*   ei = (const int*)d_in[1];
  const float* W  = (const float*)d_in[2];
  const float* b  = (const float*)d_in[3];
  float* out = (float*)d_out;

  const int N = in_sizes[0] / D;
  const int E = in_sizes[1] / 2;
  const int NBUC = (N + 63) / 64;            // 1563 for N=100k (<= MAXBUC)
  const int nb2 = (NBUC + 255) / 256;

  char* ws = (char*)d_ws;
  size_t off = 0;
  float* Wt   = (float*)(ws + off); off += (size_t)D * D * 4;        // 64 KB
  float* dis  = (float*)(ws + off); off += (size_t)N * 4;
  off = (off + 255) & ~(size_t)255;
  int* tot    = (int*)(ws + off);   off += (size_t)NBUC * 4;
  int* bsum   = (int*)(ws + off);   off += (size_t)512 * 4;
  int* boff   = (int*)(ws + off);   off += (size_t)(NBUC + 1) * 4;
  off = (off + 255) & ~(size_t)255;
  int* nodeoff = (int*)(ws + off);  off += (size_t)(N + 1) * 4;
  off = (off + 255) & ~(size_t)255;
  int* entries = (int*)(ws + off);  off += (size_t)2 * E * 4;        // 6.4 MB
  off = (off + 255) & ~(size_t)255;
  int* srcs    = (int*)(ws + off);  off += (size_t)2 * E * 4;        // 6.4 MB
  off = (off + 255) & ~(size_t)255;
  // union region: hist+bstart (3.2 MB, dead after k_scatter2) overlaps g (51.2 MB)
  int* hist    = (int*)(ws + off);
  int* bstart  = hist + (size_t)NHB * NBUC;
  float* g     = (float*)(ws + off);

  k_transpose_w<<<(D * D + 255) / 256, 256, 0, stream>>>(W, Wt);
  k_hist<<<NHB, 256, 0, stream>>>(ei, hist, E, NBUC);
  k_coltotal<<<nb2, 256, 0, stream>>>(hist, tot, NBUC);
  k_blocksum<<<nb2, 256, 0, stream>>>(tot, bsum, NBUC);
  k_scanbsum<<<1, 512, 0, stream>>>(bsum, nb2);
  k_bucketoff<<<nb2, 256, 0, stream>>>(tot, bsum, boff, NBUC);
  k_blockstart<<<NBUC, 256, 0, stream>>>(hist, boff, bstart, NBUC);
  k_scatter2<<<NHB, 256, 0, stream>>>(ei, bstart, entries, E, NBUC);
  k_sortbuc<<<NBUC, 256, 0, stream>>>(entries, boff, srcs, nodeoff, dis, N);
  k_gemm<<<(N + 127) / 128, 256, 0, stream>>>(x, Wt, b, dis, g, N);   // overwrites hist/bstart
  k_agg3<<<(N + 3) / 4, 256, 0, stream>>>(nodeoff, srcs, g, dis, out, N);
}

// Round 5
// 242.681 us; speedup vs baseline: 5.9003x; 1.4429x over previous
//
#include <hip/hip_runtime.h>

#define D 128
#define NHB 256            // blocks for hist/scatter passes
#define MAXBUC 2048        // LDS capacity for bucket counters (N <= 131072)
#define WP 136             // LDS pitch in bf16 elements (breaks 256B-stride bank aliasing)

typedef __attribute__((ext_vector_type(8))) short bf16x8;
typedef __attribute__((ext_vector_type(4))) float f32x4;

__device__ inline ushort f2b(float f) {   // fp32 -> bf16 RNE
  unsigned u = __float_as_uint(f);
  return (ushort)((u + 0x7fffu + ((u >> 16) & 1u)) >> 16);
}

// ---------------- bucketed CSR-free build (no global atomics) ----------------
// bucket(node) = node >> 6  (64 nodes per bucket)

__global__ __launch_bounds__(256) void k_hist(const int* __restrict__ ei,
                                              int* __restrict__ hist, int E, int nbuc) {
  __shared__ int h[MAXBUC];
  for (int i = threadIdx.x; i < nbuc; i += 256) h[i] = 0;
  __syncthreads();
  int per = (E + NHB - 1) / NHB;
  int e0 = blockIdx.x * per, e1 = min(E, e0 + per);
  for (int e = e0 + threadIdx.x; e < e1; e += 256) {
    int r = ei[e], c = ei[E + e];
    atomicAdd(&h[c >> 6], 1);
    atomicAdd(&h[r >> 6], 1);
  }
  __syncthreads();
  for (int i = threadIdx.x; i < nbuc; i += 256)
    hist[blockIdx.x * nbuc + i] = h[i];
}

__global__ __launch_bounds__(256) void k_coltotal(const int* __restrict__ hist,
                                                  int* __restrict__ tot, int nbuc) {
  int b = blockIdx.x * 256 + threadIdx.x;
  if (b < nbuc) {
    int s = 0;
    for (int j = 0; j < NHB; ++j) s += hist[j * nbuc + b];
    tot[b] = s;
  }
}

// single block: boff = exclusive scan of tot, boff[nbuc] = total
__global__ __launch_bounds__(256) void k_scanbuc(const int* __restrict__ tot,
                                                 int* __restrict__ boff, int nbuc) {
  __shared__ int s[256];
  __shared__ int run;
  if (threadIdx.x == 0) run = 0;
  __syncthreads();
  for (int base = 0; base < nbuc; base += 256) {
    int i = base + threadIdx.x;
    int v = (i < nbuc) ? tot[i] : 0;
    s[threadIdx.x] = v;
    __syncthreads();
    for (int o = 1; o < 256; o <<= 1) {
      int t = (threadIdx.x >= (unsigned)o) ? s[threadIdx.x - o] : 0;
      __syncthreads();
      s[threadIdx.x] += t;
      __syncthreads();
    }
    if (i < nbuc) boff[i] = run + s[threadIdx.x] - v;
    __syncthreads();
    if (threadIdx.x == 255) run += s[255];
    __syncthreads();
  }
  if (threadIdx.x == 0) boff[nbuc] = run;
}

// blockStart[j][b] = boff[b] + sum_{j'<j} hist[j'][b]
__global__ __launch_bounds__(256) void k_blockstart(const int* __restrict__ hist,
                                                    const int* __restrict__ boff,
                                                    int* __restrict__ bstart, int nbuc) {
  __shared__ int s[256];
  int b = blockIdx.x;
  int j = threadIdx.x;
  int v = hist[j * nbuc + b];
  s[j] = v;
  __syncthreads();
  for (int o = 1; o < 256; o <<= 1) {
    int t = (j >= (unsigned)o) ? s[j - o] : 0;
    __syncthreads();
    s[j] += t;
    __syncthreads();
  }
  bstart[j * nbuc + b] = boff[b] + s[j] - v;
}

// scatter packed entries (src<<6 | dest&63) using LDS int cursors
__global__ __launch_bounds__(256) void k_scatter2(const int* __restrict__ ei,
                                                  const int* __restrict__ bstart,
                                                  int* __restrict__ entries,
                                                  int E, int nbuc) {
  __shared__ int cur[MAXBUC];
  for (int i = threadIdx.x; i < nbuc; i += 256)
    cur[i] = bstart[blockIdx.x * nbuc + i];
  __syncthreads();
  int per = (E + NHB - 1) / NHB;
  int e0 = blockIdx.x * per, e1 = min(E, e0 + per);
  for (int e = e0 + threadIdx.x; e < e1; e += 256) {
    int r = ei[e], c = ei[E + e];
    int p1 = atomicAdd(&cur[c >> 6], 1);
    entries[p1] = (r << 6) | (c & 63);
    int p2 = atomicAdd(&cur[r >> 6], 1);
    entries[p2] = (c << 6) | (r & 63);
  }
}

// per-bucket counting sort by dest node -> srcs contiguous per node; nodeoff; dis
__global__ __launch_bounds__(256) void k_sortbuc(const int* __restrict__ entries,
                                                 const int* __restrict__ boff,
                                                 int* __restrict__ srcs,
                                                 int* __restrict__ nodeoff,
                                                 float* __restrict__ dis, int N) {
  __shared__ int bin[64];
  __shared__ int sc[64];
  const int b = blockIdx.x;
  const int s = boff[b], e = boff[b + 1];

  if (threadIdx.x < 64) bin[threadIdx.x] = 0;
  __syncthreads();
  for (int i = s + threadIdx.x; i < e; i += 256)
    atomicAdd(&bin[entries[i] & 63], 1);
  __syncthreads();

  int v = (threadIdx.x < 64) ? bin[threadIdx.x] : 0;
  if (threadIdx.x < 64) sc[threadIdx.x] = v;
  __syncthreads();
  for (int o = 1; o < 64; o <<= 1) {
    int t = (threadIdx.x < 64 && threadIdx.x >= (unsigned)o) ? sc[threadIdx.x - o] : 0;
    __syncthreads();
    if (threadIdx.x < 64) sc[threadIdx.x] += t;
    __syncthreads();
  }
  if (threadIdx.x < 64) {
    int start = s + sc[threadIdx.x] - v;
    bin[threadIdx.x] = start;
    int gn = b * 64 + threadIdx.x;
    if (gn < N) {
      nodeoff[gn] = start;
      dis[gn] = rsqrtf((float)(v + 1));
      if (gn == N - 1) nodeoff[N] = e;
    }
  }
  __syncthreads();

  for (int i = s + threadIdx.x; i < e; i += 256) {
    int en = entries[i];
    int p = atomicAdd(&bin[en & 63], 1);
    srcs[p] = en >> 6;
  }
}

// ---------------- MFMA GEMM: g(bf16) = dis * (x @ W^T + b) ----------------
// A[m][k]: m=lane&15 rows of x; B[k][n]=W[n][k]: lane holds 8 consecutive k of
// W row n — contiguous in W as stored, no transpose needed.
__global__ __launch_bounds__(256) void k_gemm2(
    const float* __restrict__ x, const float* __restrict__ W,
    const float* __restrict__ bias, const float* __restrict__ dis,
    ushort* __restrict__ g, int n) {
  __shared__ ushort sw[128 * WP];   // W bf16 [o][k], 34.8 KB
  __shared__ ushort sx[64 * WP];    // x tile bf16 [r][k], 17.4 KB (reused for output)
  const int tid = threadIdx.x;
  const int row0 = blockIdx.x * 64;

  // stage W (fp32 -> bf16): 128x128 = 4096 float4
  for (int i = tid; i < 128 * 32; i += 256) {
    int o = i >> 5, kg = i & 31;
    float4 v = ((const float4*)W)[i];
    ushort4 h;
    h.x = f2b(v.x); h.y = f2b(v.y); h.z = f2b(v.z); h.w = f2b(v.w);
    *(ushort4*)(&sw[o * WP + kg * 4]) = h;
  }
  // stage x tile (64 rows)
  for (int i = tid; i < 64 * 32; i += 256) {
    int r = i >> 5, kg = i & 31;
    int gr = row0 + r;
    float4 v = make_float4(0.f, 0.f, 0.f, 0.f);
    if (gr < n) v = ((const float4*)x)[(size_t)gr * 32 + kg];
    ushort4 h;
    h.x = f2b(v.x); h.y = f2b(v.y); h.z = f2b(v.z); h.w = f2b(v.w);
    *(ushort4*)(&sx[r * WP + kg * 4]) = h;
  }
  __syncthreads();

  const int wid = tid >> 6, lane = tid & 63;
  const int wr0 = wid * 16;          // wave's 16-row slice of the 64-row tile
  const int col = lane & 15, quad = lane >> 4;

  f32x4 acc[8] = {};
#pragma unroll
  for (int s = 0; s < 4; ++s) {      // K = 4 x 32
    bf16x8 a = *(const bf16x8*)(&sx[(wr0 + col) * WP + s * 32 + quad * 8]);
#pragma unroll
    for (int t = 0; t < 8; ++t) {    // 8 col-tiles of 16
      bf16x8 bfr = *(const bf16x8*)(&sw[(t * 16 + col) * WP + s * 32 + quad * 8]);
      acc[t] = __builtin_amdgcn_mfma_f32_16x16x32_bf16(a, bfr, acc[t], 0, 0, 0);
    }
  }

  // epilogue: += bias, * dis, ->bf16, bounce via LDS (sx) for coalesced stores
  float dr[4];
#pragma unroll
  for (int r = 0; r < 4; ++r) {
    int grow = row0 + wr0 + quad * 4 + r;
    dr[r] = (grow < n) ? dis[grow] : 0.f;
  }
  __syncthreads();   // everyone done reading sx
#pragma unroll
  for (int t = 0; t < 8; ++t) {
    float bcol = bias[t * 16 + col];
#pragma unroll
    for (int r = 0; r < 4; ++r) {
      int row = wr0 + quad * 4 + r;
      sx[row * WP + t * 16 + col] = f2b((acc[t][r] + bcol) * dr[r]);
    }
  }
  __syncthreads();
  for (int i = tid; i < 64 * 16; i += 256) {   // 64 rows x 16 chunks of 16B
    int r = i >> 4, c = i & 15;
    int gr = row0 + r;
    if (gr < n)
      *(uint4*)(&g[(size_t)gr * D + c * 8]) = *(const uint4*)(&sx[r * WP + c * 8]);
  }
}

// ---------------- pull aggregation from bf16 g, fp32 accumulate ----------------
__global__ __launch_bounds__(256) void k_agg4(const int* __restrict__ nodeoff,
                                              const int* __restrict__ srcs,
                                              const uint* __restrict__ g32,
                                              const float* __restrict__ dis,
                                              float* __restrict__ out, int N) {
  int w = blockIdx.x * 4 + (threadIdx.x >> 6);
  if (w >= N) return;
  int lane = threadIdx.x & 63;

  uint us = g32[(size_t)w * 64 + lane];          // self term
  float ax = __uint_as_float(us << 16);
  float ay = __uint_as_float(us & 0xffff0000u);

  int s = nodeoff[w];
  int e = nodeoff[w + 1];
  for (int base = s; base < e; base += 64) {
    int cnt = e - base; if (cnt > 64) cnt = 64;
    int my = (base + lane < e) ? srcs[base + lane] : 0;
    int k = 0;
    for (; k + 3 < cnt; k += 4) {
      int u0 = __shfl(my, k);
      int u1 = __shfl(my, k + 1);
      int u2 = __shfl(my, k + 2);
      int u3 = __shfl(my, k + 3);
      uint a = g32[(size_t)u0 * 64 + lane];
      uint b = g32[(size_t)u1 * 64 + lane];
      uint c = g32[(size_t)u2 * 64 + lane];
      uint d = g32[(size_t)u3 * 64 + lane];
      ax += __uint_as_float(a << 16) + __uint_as_float(b << 16) +
            __uint_as_float(c << 16) + __uint_as_float(d << 16);
      ay += __uint_as_float(a & 0xffff0000u) + __uint_as_float(b & 0xffff0000u) +
            __uint_as_float(c & 0xffff0000u) + __uint_as_float(d & 0xffff0000u);
    }
    for (; k < cnt; ++k) {
      int u = __shfl(my, k);
      uint a = g32[(size_t)u * 64 + lane];
      ax += __uint_as_float(a << 16);
      ay += __uint_as_float(a & 0xffff0000u);
    }
  }
  float sc = dis[w];
  float2 o;
  o.x = fmaxf(ax * sc, 0.f);
  o.y = fmaxf(ay * sc, 0.f);
  ((float2*)out)[(size_t)w * 64 + lane] = o;
}

extern "C" void kernel_launch(void* const* d_in, const int* in_sizes, int n_in,
                              void* d_out, int out_size, void* d_ws, size_t ws_size,
                              hipStream_t stream) {
  const float* x  = (const float*)d_in[0];
  const int*   ei = (const int*)d_in[1];
  const float* W  = (const float*)d_in[2];
  const float* b  = (const float*)d_in[3];
  float* out = (float*)d_out;

  const int N = in_sizes[0] / D;
  const int E = in_sizes[1] / 2;
  const int NBUC = (N + 63) / 64;            // 1563 for N=100k
  const int nb2 = (NBUC + 255) / 256;

  char* ws = (char*)d_ws;
  size_t off = 0;
  float* dis  = (float*)(ws + off); off += (size_t)N * 4;
  off = (off + 255) & ~(size_t)255;
  int* tot    = (int*)(ws + off);   off += (size_t)NBUC * 4;
  int* boff   = (int*)(ws + off);   off += (size_t)(NBUC + 1) * 4;
  off = (off + 255) & ~(size_t)255;
  int* nodeoff = (int*)(ws + off);  off += (size_t)(N + 1) * 4;
  off = (off + 255) & ~(size_t)255;
  int* entries = (int*)(ws + off);  off += (size_t)2 * E * 4;        // 6.4 MB
  off = (off + 255) & ~(size_t)255;
  int* srcs    = (int*)(ws + off);  off += (size_t)2 * E * 4;        // 6.4 MB
  off = (off + 255) & ~(size_t)255;
  // union: hist+bstart (3.2 MB, dead after k_scatter2) overlap g (25.6 MB bf16)
  int* hist    = (int*)(ws + off);
  int* bstart  = hist + (size_t)NHB * NBUC;
  ushort* g    = (ushort*)(ws + off);

  k_hist<<<NHB, 256, 0, stream>>>(ei, hist, E, NBUC);
  k_coltotal<<<nb2, 256, 0, stream>>>(hist, tot, NBUC);
  k_scanbuc<<<1, 256, 0, stream>>>(tot, boff, NBUC);
  k_blockstart<<<NBUC, 256, 0, stream>>>(hist, boff, bstart, NBUC);
  k_scatter2<<<NHB, 256, 0, stream>>>(ei, bstart, entries, E, NBUC);
  k_sortbuc<<<NBUC, 256, 0, stream>>>(entries, boff, srcs, nodeoff, dis, N);
  k_gemm2<<<NBUC, 256, 0, stream>>>(x, W, b, dis, g, N);   // overwrites hist/bstart
  k_agg4<<<(N + 3) / 4, 256, 0, stream>>>(nodeoff, srcs, (const uint*)g, dis, out, N);
}